// Round 16
// baseline (122.680 us; speedup 1.0000x reference)
//
#include <hip/hip_runtime.h>
#include <hip/hip_bf16.h>
#include <cmath>

#define NH   12
#define HD   64
#define HID  768
#define NB   2
#define SEQL 2048
#define ROWS 4096   // NB*SEQL
#define OUTW 1536   // NH*HD*2

static constexpr float NEGBIG = 1000000000000.0f;

typedef __attribute__((ext_vector_type(4)))  float f32x4;
typedef __attribute__((ext_vector_type(8)))  short short8;
typedef __attribute__((ext_vector_type(16))) float f32x16;

__device__ __forceinline__ unsigned short f2bf(float f) {
    unsigned int u = __builtin_bit_cast(unsigned int, f);
    u += 0x7FFFu + ((u >> 16) & 1u);   // round-to-nearest-even
    return (unsigned short)(u >> 16);
}

__device__ __forceinline__ short8 cvt8(const float* __restrict__ p) {
    float4 v0 = *reinterpret_cast<const float4*>(p);
    float4 v1 = *reinterpret_cast<const float4*>(p + 4);
    short8 g;
    g[0] = (short)f2bf(v0.x); g[1] = (short)f2bf(v0.y);
    g[2] = (short)f2bf(v0.z); g[3] = (short)f2bf(v0.w);
    g[4] = (short)f2bf(v1.x); g[5] = (short)f2bf(v1.y);
    g[6] = (short)f2bf(v1.z); g[7] = (short)f2bf(v1.w);
    return g;
}

// Masked-tile fill: fid in [0,2880) enumerates (bh, nt, mt) with mt < nt.
__device__ __forceinline__ void fill_tile(int fid, int tid,
                                          const int* __restrict__ mask,
                                          float* __restrict__ out) {
    const int bh = fid / 120;
    int j = fid % 120;
    int ntv = 1;
    while (j >= ntv) { j -= ntv; ++ntv; }
    const int nt = ntv, mt = j;          // mt < nt
    const int bI = bh / NH;
    float* outbase = out + (size_t)bh * SEQL * SEQL;
    const int cg = tid & 31;
    const int r0 = tid >> 5;
    const int m0 = mt * 128 + cg * 4;
    const int4 mi = *reinterpret_cast<const int4*>(mask + bI * SEQL + m0);
    f32x4 v;
    v.x = ((float)mi.x - 2.0f) * (NEGBIG * 0.125f);
    v.y = ((float)mi.y - 2.0f) * (NEGBIG * 0.125f);
    v.z = ((float)mi.z - 2.0f) * (NEGBIG * 0.125f);
    v.w = ((float)mi.w - 2.0f) * (NEGBIG * 0.125f);
    float* ob = outbase + (size_t)(nt * 128) * SEQL + m0;
#pragma unroll
    for (int jj = 0; jj < 16; ++jj) {
        int row = r0 + 8 * jj;
        __builtin_nontemporal_store(v, reinterpret_cast<f32x4*>(ob + (size_t)row * SEQL));
    }
}

// ---- K0: prep (convert W; rope table) + 700 fill tiles ----
#define WQ (OUTW * HID / 4)          // 294912 float4 groups -> 1152 blocks
#define RQ (SEQL * 32)               // 65536 -> 256 blocks
#define PREP_BLOCKS 1408
#define FILL_PREP   700
#define FILL_P1     2180
__global__ void k_prep(const float* __restrict__ W,
                       unsigned short* __restrict__ Wbf, float2* __restrict__ rtab,
                       const int* __restrict__ mask, float* __restrict__ out) {
    if (blockIdx.x >= PREP_BLOCKS) {
        fill_tile(blockIdx.x - PREP_BLOCKS, threadIdx.x, mask, out);
        return;
    }
    int i = blockIdx.x * blockDim.x + threadIdx.x;
    if (i < WQ) {
        float4 v = reinterpret_cast<const float4*>(W)[i];
        ushort4 o;
        o.x = f2bf(v.x); o.y = f2bf(v.y); o.z = f2bf(v.z); o.w = f2bf(v.w);
        reinterpret_cast<ushort4*>(Wbf)[i] = o;
    } else if (i < WQ + RQ) {
        int idx = i - WQ;
        int n = idx >> 5, d = idx & 31;
        float theta = exp2f(-(float)d * (13.287712379549449f / 32.0f)); // 10000^(-d/32)
        float ang = (float)n * theta;
        rtab[idx] = make_float2(sinf(ang), cosf(ang));
    }
}

// ---- Phase 1: K1 proj GEMM (bids 0..767, X read f32 + in-reg convert)
//      + 2180 fill tiles (bids 768..2947) ----
__global__ __launch_bounds__(256, 4) void k_proj_fill(
    const float* __restrict__ X,              // [4096][768] f32
    const unsigned short* __restrict__ Wbf,   // [1536][768] bf16
    const float*  __restrict__ bias,          // [1536]
    const float2* __restrict__ rtab,          // [2048][32]
    unsigned short* __restrict__ Qbf,         // [2][12][2048][64] bf16
    unsigned short* __restrict__ Kbf,
    const int* __restrict__ mask,             // [2][2048]
    float* __restrict__ out)                  // [2][12][2048][2048]
{
    const int bid = blockIdx.x;
    const int tid = threadIdx.x;

    if (bid >= 768) {
        fill_tile(FILL_PREP + (bid - 768), tid, mask, out);
        return;
    }

    // ---- K1: projection GEMM + RoPE ----
    const int newbid = (bid & 7) * 96 + (bid >> 3); // bijective: 768 = 8*96
    const int slab = newbid / 12;                   // 0..63
    const int head = newbid % 12;                   // 0..11
    const int row0 = slab * 64;
    const int lane = tid & 63;
    const int w    = tid >> 6;
    const int wr = w & 1, wc = w >> 1;
    const int l31 = lane & 31, lhi = lane >> 5;
    const int x7  = l31 & 7;

    __shared__ __align__(16) unsigned short smem[12288];

    f32x16 acc[2];
    {
        float bj0 = bias[head * 128 + wc * 64 + l31];
        float bj1 = bias[head * 128 + wc * 64 + 32 + l31];
#pragma unroll
        for (int r = 0; r < 16; ++r) { acc[0][r] = bj0; acc[1][r] = bj1; }
    }

    const float* Abase = X + (size_t)row0 * HID;
    const unsigned short* Bbase = Wbf + (size_t)(head * 128) * HID;

    short8 ga[2], gb[4];
#pragma unroll
    for (int r = 0; r < 2; ++r) {
        int idx = tid + 256 * r, row = idx >> 3, s = idx & 7;
        ga[r] = cvt8(Abase + (size_t)row * HID + s * 8);
    }
#pragma unroll
    for (int r = 0; r < 4; ++r) {
        int idx = tid + 256 * r, row = idx >> 3, s = idx & 7;
        gb[r] = *reinterpret_cast<const short8*>(Bbase + (size_t)row * HID + s * 8);
    }
#pragma unroll
    for (int r = 0; r < 2; ++r) {
        int idx = tid + 256 * r, row = idx >> 3, s = idx & 7, ws = s ^ (row & 7);
        *reinterpret_cast<short8*>(smem + row * 64 + ws * 8) = ga[r];
    }
#pragma unroll
    for (int r = 0; r < 4; ++r) {
        int idx = tid + 256 * r, row = idx >> 3, s = idx & 7, ws = s ^ (row & 7);
        *reinterpret_cast<short8*>(smem + 4096 + row * 64 + ws * 8) = gb[r];
    }

    for (int t = 0; t < 12; ++t) {
        __syncthreads();
        if (t < 11) {
            const int kk = (t + 1) * 64;
#pragma unroll
            for (int r = 0; r < 2; ++r) {
                int idx = tid + 256 * r, row = idx >> 3, s = idx & 7;
                ga[r] = cvt8(Abase + (size_t)row * HID + kk + s * 8);
            }
#pragma unroll
            for (int r = 0; r < 4; ++r) {
                int idx = tid + 256 * r, row = idx >> 3, s = idx & 7;
                gb[r] = *reinterpret_cast<const short8*>(Bbase + (size_t)row * HID + kk + s * 8);
            }
        }
#pragma unroll
        for (int ks = 0; ks < 4; ++ks) {
            int sl = (ks * 2 + lhi) ^ x7;
            short8 a  = *reinterpret_cast<const short8*>(smem + (wr * 32 + l31) * 64 + sl * 8);
            short8 b0 = *reinterpret_cast<const short8*>(smem + 4096 + (wc * 64 + l31) * 64 + sl * 8);
            short8 b1 = *reinterpret_cast<const short8*>(smem + 4096 + (wc * 64 + 32 + l31) * 64 + sl * 8);
            acc[0] = __builtin_amdgcn_mfma_f32_32x32x16_bf16(a, b0, acc[0], 0, 0, 0);
            acc[1] = __builtin_amdgcn_mfma_f32_32x32x16_bf16(a, b1, acc[1], 0, 0, 0);
        }
        if (t < 11) {
            __syncthreads();
#pragma unroll
            for (int r = 0; r < 2; ++r) {
                int idx = tid + 256 * r, row = idx >> 3, s = idx & 7, ws = s ^ (row & 7);
                *reinterpret_cast<short8*>(smem + row * 64 + ws * 8) = ga[r];
            }
#pragma unroll
            for (int r = 0; r < 4; ++r) {
                int idx = tid + 256 * r, row = idx >> 3, s = idx & 7, ws = s ^ (row & 7);
                *reinterpret_cast<short8*>(smem + 4096 + row * 64 + ws * 8) = gb[r];
            }
        }
    }
    __syncthreads();

    // RoPE epilogue: two 32-row phases, hs[32][132] f32 in smem.
    float (*hs)[132] = reinterpret_cast<float (*)[132]>(smem);
    for (int s = 0; s < 2; ++s) {
        if (wr == s) {
#pragma unroll
            for (int j = 0; j < 2; ++j)
#pragma unroll
                for (int r = 0; r < 16; ++r) {
                    int rr = (r & 3) + 8 * (r >> 2) + 4 * lhi;  // 0..31
                    hs[rr][wc * 64 + j * 32 + l31] = acc[j][r];
                }
        }
        __syncthreads();
#pragma unroll 4
        for (int it = 0; it < 8; ++it) {
            int f   = tid + 256 * it;    // 0..2047
            int row = f >> 6;            // 0..31
            int u   = f & 63;
            int isK = u >> 5;
            int dp  = u & 31;
            int d0  = 2 * dp, d1 = d0 + 1;
            int cb  = isK * 64;
            int grow = row0 + s * 32 + row;
            int bI = grow >> 11;
            int n  = grow & 2047;
            float2 sc = rtab[n * 32 + dp];
            float v0 = hs[row][cb + d0];
            float v1 = hs[row][cb + d1];
            int p0 = (d0 < 32) ? (2 * d0 + 1) : (2 * d0 - 64);
            int p1 = (d1 < 32) ? (2 * d1 + 1) : (2 * d1 - 64);
            float pv0 = hs[row][cb + p0];
            float pv1 = hs[row][cb + p1];
            float sg0 = (d0 < 32) ? -1.0f : 1.0f;
            float sg1 = (d1 < 32) ? -1.0f : 1.0f;
            ushort2 st;
            st.x = f2bf(v0 * sc.y + sg0 * pv0 * sc.x);
            st.y = f2bf(v1 * sc.y + sg1 * pv1 * sc.x);
            unsigned short* dst = isK ? (unsigned short*)Kbf : (unsigned short*)Qbf;
            size_t idx = ((size_t)(bI * NH + head) * SEQL + n) * HD + d0;
            *reinterpret_cast<ushort2*>(dst + idx) = st;
        }
        __syncthreads();
    }
}

// ---- Phase 2: K2c compute tiles only; grid 3264 = 8*408 ----
__global__ __launch_bounds__(256) void k_logits(
    const unsigned short* __restrict__ Qbf,
    const unsigned short* __restrict__ Kbf,
    const int* __restrict__ mask,    // [2][2048]
    float* __restrict__ out)         // [2][12][2048][2048]
{
    const int bid = blockIdx.x;
    const int newbid = (bid & 7) * 408 + (bid >> 3);   // bijective: 3264 = 8*408
    const int tid = threadIdx.x;

    const int bh = newbid / 136;
    int j = newbid % 136;
    int ntv = 0;
    while (j >= 16 - ntv) { j -= 16 - ntv; ++ntv; }
    const int nt = ntv, mt = ntv + j;           // mt >= nt
    const int bI = bh / NH;
    float* outbase = out + (size_t)bh * SEQL * SEQL;

    const int lane = tid & 63;
    const int w = tid >> 6;
    const int rowHalf = w & 1, colHalf = w >> 1;
    const int l31 = lane & 31, lhi = lane >> 5;
    const int n0 = nt * 128 + rowHalf * 64;
    const int m0 = mt * 128 + colHalf * 64;

    f32x16 acc[2][2];
#pragma unroll
    for (int i = 0; i < 2; ++i)
#pragma unroll
        for (int jj = 0; jj < 2; ++jj)
#pragma unroll
            for (int r = 0; r < 16; ++r) acc[i][jj][r] = 0.0f;

    const unsigned short* Aq = Qbf + ((size_t)bh * SEQL + n0 + l31) * HD + 8 * lhi;
    const unsigned short* Bk = Kbf + ((size_t)bh * SEQL + m0 + l31) * HD + 8 * lhi;
#pragma unroll
    for (int t2 = 0; t2 < 4; ++t2) {
        short8 a0 = *reinterpret_cast<const short8*>(Aq + 16 * t2);
        short8 a1 = *reinterpret_cast<const short8*>(Aq + 32 * HD + 16 * t2);
        short8 b0 = *reinterpret_cast<const short8*>(Bk + 16 * t2);
        short8 b1 = *reinterpret_cast<const short8*>(Bk + 32 * HD + 16 * t2);
        acc[0][0] = __builtin_amdgcn_mfma_f32_32x32x16_bf16(a0, b0, acc[0][0], 0, 0, 0);
        acc[0][1] = __builtin_amdgcn_mfma_f32_32x32x16_bf16(a0, b1, acc[0][1], 0, 0, 0);
        acc[1][0] = __builtin_amdgcn_mfma_f32_32x32x16_bf16(a1, b0, acc[1][0], 0, 0, 0);
        acc[1][1] = __builtin_amdgcn_mfma_f32_32x32x16_bf16(a1, b1, acc[1][1], 0, 0, 0);
    }

    // LDS-transpose epilogue: two 32-row slabs (i = 0,1), f32x4 NT stores.
    __shared__ float tl[64][128];   // 32 KB
#pragma unroll
    for (int i = 0; i < 2; ++i) {
#pragma unroll
        for (int jj = 0; jj < 2; ++jj) {
#pragma unroll
            for (int r = 0; r < 16; ++r) {
                int rr = (r & 3) + 8 * (r >> 2) + 4 * lhi;    // 0..31
                tl[rowHalf * 32 + rr][colHalf * 64 + jj * 32 + l31] = acc[i][jj][r];
            }
        }
        __syncthreads();
#pragma unroll
        for (int it = 0; it < 8; ++it) {
            int f   = tid + 256 * it;      // 0..2047
            int lr  = f >> 5;              // 0..63
            int cg  = f & 31;              // 0..31 -> 4 cols
            int grow = nt * 128 + (lr >> 5) * 64 + i * 32 + (lr & 31);
            int gcol = mt * 128 + cg * 4;
            const int4 mi = *reinterpret_cast<const int4*>(mask + bI * SEQL + gcol);
            f32x4 v = *reinterpret_cast<const f32x4*>(&tl[lr][cg * 4]);
            float pads[4] = {(float)mi.x, (float)mi.y, (float)mi.z, (float)mi.w};
#pragma unroll
            for (int e = 0; e < 4; ++e) {
                float vv = v[e] * pads[e] - (1.0f - pads[e]) * NEGBIG;
                if (gcol + e < grow) vv -= NEGBIG;
                v[e] = vv * 0.125f;
            }
            __builtin_nontemporal_store(v, reinterpret_cast<f32x4*>(outbase + (size_t)grow * SEQL + gcol));
        }
        __syncthreads();
    }
}

extern "C" void kernel_launch(void* const* d_in, const int* in_sizes, int n_in,
                              void* d_out, int out_size, void* d_ws, size_t ws_size,
                              hipStream_t stream) {
    const float* x    = (const float*)d_in[0];
    const int*   mask = (const int*)d_in[1];
    const float* W    = (const float*)d_in[2];
    const float* bias = (const float*)d_in[3];
    float* out = (float*)d_out;

    char* ws = (char*)d_ws;
    unsigned short* Wbf = (unsigned short*)(ws);                 // 2,359,296 B
    unsigned short* Qbf = (unsigned short*)(ws + 2359296);       // 6,291,456 B
    unsigned short* Kbf = (unsigned short*)(ws + 8650752);       // 6,291,456 B
    float2*         rtab = (float2*)(ws + 14942208);             //   524,288 B

    k_prep<<<dim3(PREP_BLOCKS + FILL_PREP), dim3(256), 0, stream>>>(W, Wbf, rtab, mask, out);
    // ATTRIBUTION PROBE #3: k_proj_fill launched twice (idempotent).
    // p1_warm = total_this_round - 90.0 µs. Remove duplicate next round.
    k_proj_fill<<<dim3(768 + FILL_P1), dim3(256), 0, stream>>>(x, Wbf, bias, rtab, Qbf, Kbf, mask, out);
    k_proj_fill<<<dim3(768 + FILL_P1), dim3(256), 0, stream>>>(x, Wbf, bias, rtab, Qbf, Kbf, mask, out);
    k_logits<<<dim3(3264), dim3(256), 0, stream>>>(Qbf, Kbf, mask, out);
}

// Round 17
// 100.887 us; speedup vs baseline: 1.2160x; 1.2160x over previous
//
#include <hip/hip_runtime.h>
#include <hip/hip_bf16.h>
#include <cmath>

#define NH   12
#define HD   64
#define HID  768
#define NB   2
#define SEQL 2048
#define ROWS 4096   // NB*SEQL
#define OUTW 1536   // NH*HD*2

static constexpr float NEGBIG = 1000000000000.0f;

typedef __attribute__((ext_vector_type(4)))  float f32x4;
typedef __attribute__((ext_vector_type(8)))  short short8;
typedef __attribute__((ext_vector_type(16))) float f32x16;

__device__ __forceinline__ unsigned short f2bf(float f) {
    unsigned int u = __builtin_bit_cast(unsigned int, f);
    u += 0x7FFFu + ((u >> 16) & 1u);   // round-to-nearest-even
    return (unsigned short)(u >> 16);
}

// Masked-tile fill: fid in [0,2880) enumerates (bh, nt, mt) with mt < nt.
__device__ __forceinline__ void fill_tile(int fid, int tid,
                                          const int* __restrict__ mask,
                                          float* __restrict__ out) {
    const int bh = fid / 120;
    int j = fid % 120;
    int ntv = 1;
    while (j >= ntv) { j -= ntv; ++ntv; }
    const int nt = ntv, mt = j;          // mt < nt
    const int bI = bh / NH;
    float* outbase = out + (size_t)bh * SEQL * SEQL;
    const int cg = tid & 31;
    const int r0 = tid >> 5;
    const int m0 = mt * 128 + cg * 4;
    const int4 mi = *reinterpret_cast<const int4*>(mask + bI * SEQL + m0);
    f32x4 v;
    v.x = ((float)mi.x - 2.0f) * (NEGBIG * 0.125f);
    v.y = ((float)mi.y - 2.0f) * (NEGBIG * 0.125f);
    v.z = ((float)mi.z - 2.0f) * (NEGBIG * 0.125f);
    v.w = ((float)mi.w - 2.0f) * (NEGBIG * 0.125f);
    float* ob = outbase + (size_t)(nt * 128) * SEQL + m0;
#pragma unroll
    for (int jj = 0; jj < 16; ++jj) {
        int row = r0 + 8 * jj;
        __builtin_nontemporal_store(v, reinterpret_cast<f32x4*>(ob + (size_t)row * SEQL));
    }
}

// ---- K0: prep (convert X, W -> bf16; rope table) + 700 fill tiles ----
#define XQ (ROWS * HID / 4)          // 786432 float4 groups -> 3072 blocks
#define WQ (OUTW * HID / 4)          // 294912 -> 1152 blocks
#define RQ (SEQL * 32)               // 65536 -> 256 blocks
#define PREP_BLOCKS 4480
#define FILL_PREP   700
#define FILL_P1     2180
__global__ void k_prep(const float* __restrict__ X, const float* __restrict__ W,
                       unsigned short* __restrict__ Xbf, unsigned short* __restrict__ Wbf,
                       float2* __restrict__ rtab,
                       const int* __restrict__ mask, float* __restrict__ out) {
    if (blockIdx.x >= PREP_BLOCKS) {
        fill_tile(blockIdx.x - PREP_BLOCKS, threadIdx.x, mask, out);
        return;
    }
    int i = blockIdx.x * blockDim.x + threadIdx.x;
    if (i < XQ + WQ) {
        const float* src = (i < XQ) ? X : W;
        unsigned short* dst = (i < XQ) ? Xbf : Wbf;
        int k = (i < XQ) ? i : i - XQ;
        float4 v = reinterpret_cast<const float4*>(src)[k];
        ushort4 o;
        o.x = f2bf(v.x); o.y = f2bf(v.y); o.z = f2bf(v.z); o.w = f2bf(v.w);
        reinterpret_cast<ushort4*>(dst)[k] = o;
    } else if (i < XQ + WQ + RQ) {
        int idx = i - (XQ + WQ);
        int n = idx >> 5, d = idx & 31;
        float theta = exp2f(-(float)d * (13.287712379549449f / 32.0f)); // 10000^(-d/32)
        float ang = (float)n * theta;
        rtab[idx] = make_float2(sinf(ang), cosf(ang));
    }
}

// ---- Phase 1: K1 (bids 0..767, R10 dbuf structure) + 2180 fill tiles ----
// K1: 64x128 tile, BK=64, double-buffered 48 KB LDS, 1 barrier/iter,
// bf16 staging from Xbf/Wbf, bias folded in acc. 3 blocks/CU.
__global__ __launch_bounds__(256, 3) void k_proj_fill(
    const unsigned short* __restrict__ Xbf,   // [4096][768] bf16
    const unsigned short* __restrict__ Wbf,   // [1536][768] bf16
    const float*  __restrict__ bias,          // [1536]
    const float2* __restrict__ rtab,          // [2048][32]
    unsigned short* __restrict__ Qbf,         // [2][12][2048][64] bf16
    unsigned short* __restrict__ Kbf,
    const int* __restrict__ mask,             // [2][2048]
    float* __restrict__ out)                  // [2][12][2048][2048]
{
    const int bid = blockIdx.x;
    const int tid = threadIdx.x;

    if (bid >= 768) {
        fill_tile(FILL_PREP + (bid - 768), tid, mask, out);
        return;
    }

    const int newbid = (bid & 7) * 96 + (bid >> 3); // bijective: 768 = 8*96
    const int slab = newbid / 12;                   // 0..63
    const int head = newbid % 12;                   // 0..11
    const int row0 = slab * 64;
    const int lane = tid & 63;
    const int w    = tid >> 6;
    const int wr = w & 1, wc = w >> 1;
    const int l31 = lane & 31, lhi = lane >> 5;
    const int x7  = l31 & 7;

    // 48 KB: A bufs [0,4096),[4096,8192); B bufs [8192,16384),[16384,24576) shorts
    __shared__ __align__(16) unsigned short smem[24576];

    f32x16 acc[2];
    {
        float bj0 = bias[head * 128 + wc * 64 + l31];
        float bj1 = bias[head * 128 + wc * 64 + 32 + l31];
#pragma unroll
        for (int r = 0; r < 16; ++r) { acc[0][r] = bj0; acc[1][r] = bj1; }
    }

    const unsigned short* Abase = Xbf + (size_t)row0 * HID;
    const unsigned short* Bbase = Wbf + (size_t)(head * 128) * HID;

    short8 ga[2], gb[4];
    // stage tile 0
#pragma unroll
    for (int r = 0; r < 2; ++r) {
        int idx = tid + 256 * r, row = idx >> 3, s = idx & 7;
        ga[r] = *reinterpret_cast<const short8*>(Abase + (size_t)row * HID + s * 8);
    }
#pragma unroll
    for (int r = 0; r < 4; ++r) {
        int idx = tid + 256 * r, row = idx >> 3, s = idx & 7;
        gb[r] = *reinterpret_cast<const short8*>(Bbase + (size_t)row * HID + s * 8);
    }
#pragma unroll
    for (int r = 0; r < 2; ++r) {
        int idx = tid + 256 * r, row = idx >> 3, s = idx & 7, ws = s ^ (row & 7);
        *reinterpret_cast<short8*>(smem + row * 64 + ws * 8) = ga[r];
    }
#pragma unroll
    for (int r = 0; r < 4; ++r) {
        int idx = tid + 256 * r, row = idx >> 3, s = idx & 7, ws = s ^ (row & 7);
        *reinterpret_cast<short8*>(smem + 8192 + row * 64 + ws * 8) = gb[r];
    }
    __syncthreads();

    for (int t = 0; t < 12; ++t) {
        const int cur = t & 1;
        if (t < 11) {
            const int kk = (t + 1) * 64;
#pragma unroll
            for (int r = 0; r < 2; ++r) {
                int idx = tid + 256 * r, row = idx >> 3, s = idx & 7;
                ga[r] = *reinterpret_cast<const short8*>(Abase + (size_t)row * HID + kk + s * 8);
            }
#pragma unroll
            for (int r = 0; r < 4; ++r) {
                int idx = tid + 256 * r, row = idx >> 3, s = idx & 7;
                gb[r] = *reinterpret_cast<const short8*>(Bbase + (size_t)row * HID + kk + s * 8);
            }
        }
        const unsigned short* Ab = smem + cur * 4096;
        const unsigned short* Bb = smem + 8192 + cur * 8192;
#pragma unroll
        for (int ks = 0; ks < 4; ++ks) {
            int sl = (ks * 2 + lhi) ^ x7;
            short8 a  = *reinterpret_cast<const short8*>(Ab + (wr * 32 + l31) * 64 + sl * 8);
            short8 b0 = *reinterpret_cast<const short8*>(Bb + (wc * 64 + l31) * 64 + sl * 8);
            short8 b1 = *reinterpret_cast<const short8*>(Bb + (wc * 64 + 32 + l31) * 64 + sl * 8);
            acc[0] = __builtin_amdgcn_mfma_f32_32x32x16_bf16(a, b0, acc[0], 0, 0, 0);
            acc[1] = __builtin_amdgcn_mfma_f32_32x32x16_bf16(a, b1, acc[1], 0, 0, 0);
        }
        if (t < 11) {
            const int nxt = cur ^ 1;
#pragma unroll
            for (int r = 0; r < 2; ++r) {
                int idx = tid + 256 * r, row = idx >> 3, s = idx & 7, ws = s ^ (row & 7);
                *reinterpret_cast<short8*>(smem + nxt * 4096 + row * 64 + ws * 8) = ga[r];
            }
#pragma unroll
            for (int r = 0; r < 4; ++r) {
                int idx = tid + 256 * r, row = idx >> 3, s = idx & 7, ws = s ^ (row & 7);
                *reinterpret_cast<short8*>(smem + 8192 + nxt * 8192 + row * 64 + ws * 8) = gb[r];
            }
        }
        __syncthreads();
    }

    // RoPE epilogue, single 64-row phase: hs[64][132] f32 = 33.8 KB in smem.
    float (*hs)[132] = reinterpret_cast<float (*)[132]>(smem);
#pragma unroll
    for (int j = 0; j < 2; ++j)
#pragma unroll
        for (int r = 0; r < 16; ++r) {
            int rr = (r & 3) + 8 * (r >> 2) + 4 * lhi;  // 0..31
            hs[wr * 32 + rr][wc * 64 + j * 32 + l31] = acc[j][r];
        }
    __syncthreads();
    // 64 rows x 32 pairs x 2 (q,k) = 4096 ushort2 items, 16 per thread
#pragma unroll 4
    for (int it = 0; it < 16; ++it) {
        int f   = tid + 256 * it;    // 0..4095
        int row = f >> 6;            // 0..63
        int u   = f & 63;
        int isK = u >> 5;
        int dp  = u & 31;
        int d0  = 2 * dp, d1 = d0 + 1;
        int cb  = isK * 64;
        int grow = row0 + row;
        int bI = grow >> 11;
        int n  = grow & 2047;
        float2 sc = rtab[n * 32 + dp];
        float v0 = hs[row][cb + d0];
        float v1 = hs[row][cb + d1];
        int p0 = (d0 < 32) ? (2 * d0 + 1) : (2 * d0 - 64);
        int p1 = (d1 < 32) ? (2 * d1 + 1) : (2 * d1 - 64);
        float pv0 = hs[row][cb + p0];
        float pv1 = hs[row][cb + p1];
        float sg0 = (d0 < 32) ? -1.0f : 1.0f;
        float sg1 = (d1 < 32) ? -1.0f : 1.0f;
        ushort2 st;
        st.x = f2bf(v0 * sc.y + sg0 * pv0 * sc.x);
        st.y = f2bf(v1 * sc.y + sg1 * pv1 * sc.x);
        unsigned short* dst = isK ? (unsigned short*)Kbf : (unsigned short*)Qbf;
        size_t idx = ((size_t)(bI * NH + head) * SEQL + n) * HD + d0;
        *reinterpret_cast<ushort2*>(dst + idx) = st;
    }
}

// ---- Phase 2: K2c compute tiles only; grid 3264 = 8*408 ----
__global__ __launch_bounds__(256) void k_logits(
    const unsigned short* __restrict__ Qbf,
    const unsigned short* __restrict__ Kbf,
    const int* __restrict__ mask,    // [2][2048]
    float* __restrict__ out)         // [2][12][2048][2048]
{
    const int bid = blockIdx.x;
    const int newbid = (bid & 7) * 408 + (bid >> 3);   // bijective: 3264 = 8*408
    const int tid = threadIdx.x;

    const int bh = newbid / 136;
    int j = newbid % 136;
    int ntv = 0;
    while (j >= 16 - ntv) { j -= 16 - ntv; ++ntv; }
    const int nt = ntv, mt = ntv + j;           // mt >= nt
    const int bI = bh / NH;
    float* outbase = out + (size_t)bh * SEQL * SEQL;

    const int lane = tid & 63;
    const int w = tid >> 6;
    const int rowHalf = w & 1, colHalf = w >> 1;
    const int l31 = lane & 31, lhi = lane >> 5;
    const int n0 = nt * 128 + rowHalf * 64;
    const int m0 = mt * 128 + colHalf * 64;

    f32x16 acc[2][2];
#pragma unroll
    for (int i = 0; i < 2; ++i)
#pragma unroll
        for (int jj = 0; jj < 2; ++jj)
#pragma unroll
            for (int r = 0; r < 16; ++r) acc[i][jj][r] = 0.0f;

    const unsigned short* Aq = Qbf + ((size_t)bh * SEQL + n0 + l31) * HD + 8 * lhi;
    const unsigned short* Bk = Kbf + ((size_t)bh * SEQL + m0 + l31) * HD + 8 * lhi;
#pragma unroll
    for (int t2 = 0; t2 < 4; ++t2) {
        short8 a0 = *reinterpret_cast<const short8*>(Aq + 16 * t2);
        short8 a1 = *reinterpret_cast<const short8*>(Aq + 32 * HD + 16 * t2);
        short8 b0 = *reinterpret_cast<const short8*>(Bk + 16 * t2);
        short8 b1 = *reinterpret_cast<const short8*>(Bk + 32 * HD + 16 * t2);
        acc[0][0] = __builtin_amdgcn_mfma_f32_32x32x16_bf16(a0, b0, acc[0][0], 0, 0, 0);
        acc[0][1] = __builtin_amdgcn_mfma_f32_32x32x16_bf16(a0, b1, acc[0][1], 0, 0, 0);
        acc[1][0] = __builtin_amdgcn_mfma_f32_32x32x16_bf16(a1, b0, acc[1][0], 0, 0, 0);
        acc[1][1] = __builtin_amdgcn_mfma_f32_32x32x16_bf16(a1, b1, acc[1][1], 0, 0, 0);
    }

    // LDS-transpose epilogue: two 32-row slabs (i = 0,1), f32x4 NT stores.
    __shared__ float tl[64][128];   // 32 KB
#pragma unroll
    for (int i = 0; i < 2; ++i) {
#pragma unroll
        for (int jj = 0; jj < 2; ++jj) {
#pragma unroll
            for (int r = 0; r < 16; ++r) {
                int rr = (r & 3) + 8 * (r >> 2) + 4 * lhi;    // 0..31
                tl[rowHalf * 32 + rr][colHalf * 64 + jj * 32 + l31] = acc[i][jj][r];
            }
        }
        __syncthreads();
#pragma unroll
        for (int it = 0; it < 8; ++it) {
            int f   = tid + 256 * it;      // 0..2047
            int lr  = f >> 5;              // 0..63
            int cg  = f & 31;              // 0..31 -> 4 cols
            int grow = nt * 128 + (lr >> 5) * 64 + i * 32 + (lr & 31);
            int gcol = mt * 128 + cg * 4;
            const int4 mi = *reinterpret_cast<const int4*>(mask + bI * SEQL + gcol);
            f32x4 v = *reinterpret_cast<const f32x4*>(&tl[lr][cg * 4]);
            float pads[4] = {(float)mi.x, (float)mi.y, (float)mi.z, (float)mi.w};
#pragma unroll
            for (int e = 0; e < 4; ++e) {
                float vv = v[e] * pads[e] - (1.0f - pads[e]) * NEGBIG;
                if (gcol + e < grow) vv -= NEGBIG;
                v[e] = vv * 0.125f;
            }
            __builtin_nontemporal_store(v, reinterpret_cast<f32x4*>(outbase + (size_t)grow * SEQL + gcol));
        }
        __syncthreads();
    }
}

extern "C" void kernel_launch(void* const* d_in, const int* in_sizes, int n_in,
                              void* d_out, int out_size, void* d_ws, size_t ws_size,
                              hipStream_t stream) {
    const float* x    = (const float*)d_in[0];
    const int*   mask = (const int*)d_in[1];
    const float* W    = (const float*)d_in[2];
    const float* bias = (const float*)d_in[3];
    float* out = (float*)d_out;

    char* ws = (char*)d_ws;
    unsigned short* Xbf = (unsigned short*)(ws);                 // 6,291,456 B
    unsigned short* Wbf = (unsigned short*)(ws + 6291456);       // 2,359,296 B
    unsigned short* Qbf = (unsigned short*)(ws + 8650752);       // 6,291,456 B
    unsigned short* Kbf = (unsigned short*)(ws + 14942208);      // 6,291,456 B
    float2*         rtab = (float2*)(ws + 21233664);             //   524,288 B

    k_prep<<<dim3(PREP_BLOCKS + FILL_PREP), dim3(256), 0, stream>>>(x, W, Xbf, Wbf, rtab, mask, out);
    k_proj_fill<<<dim3(768 + FILL_P1), dim3(256), 0, stream>>>(Xbf, Wbf, bias, rtab, Qbf, Kbf, mask, out);
    k_logits<<<dim3(3264), dim3(256), 0, stream>>>(Qbf, Kbf, mask, out);
}

// Round 18
// 87.826 us; speedup vs baseline: 1.3969x; 1.1487x over previous
//
#include <hip/hip_runtime.h>
#include <hip/hip_bf16.h>
#include <cmath>

#define NH   12
#define HD   64
#define HID  768
#define NB   2
#define SEQL 2048
#define ROWS 4096   // NB*SEQL
#define OUTW 1536   // NH*HD*2

static constexpr float NEGBIG = 1000000000000.0f;

typedef __attribute__((ext_vector_type(4)))  float f32x4;
typedef __attribute__((ext_vector_type(8)))  short short8;
typedef __attribute__((ext_vector_type(16))) float f32x16;

__device__ __forceinline__ unsigned short f2bf(float f) {
    unsigned int u = __builtin_bit_cast(unsigned int, f);
    u += 0x7FFFu + ((u >> 16) & 1u);   // round-to-nearest-even
    return (unsigned short)(u >> 16);
}

__device__ __forceinline__ short8 cvt8(const float* __restrict__ p) {
    float4 v0 = *reinterpret_cast<const float4*>(p);
    float4 v1 = *reinterpret_cast<const float4*>(p + 4);
    short8 g;
    g[0] = (short)f2bf(v0.x); g[1] = (short)f2bf(v0.y);
    g[2] = (short)f2bf(v0.z); g[3] = (short)f2bf(v0.w);
    g[4] = (short)f2bf(v1.x); g[5] = (short)f2bf(v1.y);
    g[6] = (short)f2bf(v1.z); g[7] = (short)f2bf(v1.w);
    return g;
}

// Masked-tile fill: fid in [0,2880) enumerates (bh, nt, mt) with mt < nt.
__device__ __forceinline__ void fill_tile(int fid, int tid,
                                          const int* __restrict__ mask,
                                          float* __restrict__ out) {
    const int bh = fid / 120;
    int j = fid % 120;
    int ntv = 1;
    while (j >= ntv) { j -= ntv; ++ntv; }
    const int nt = ntv, mt = j;          // mt < nt
    const int bI = bh / NH;
    float* outbase = out + (size_t)bh * SEQL * SEQL;
    const int cg = tid & 31;
    const int r0 = tid >> 5;
    const int m0 = mt * 128 + cg * 4;
    const int4 mi = *reinterpret_cast<const int4*>(mask + bI * SEQL + m0);
    f32x4 v;
    v.x = ((float)mi.x - 2.0f) * (NEGBIG * 0.125f);
    v.y = ((float)mi.y - 2.0f) * (NEGBIG * 0.125f);
    v.z = ((float)mi.z - 2.0f) * (NEGBIG * 0.125f);
    v.w = ((float)mi.w - 2.0f) * (NEGBIG * 0.125f);
    float* ob = outbase + (size_t)(nt * 128) * SEQL + m0;
#pragma unroll
    for (int jj = 0; jj < 16; ++jj) {
        int row = r0 + 8 * jj;
        __builtin_nontemporal_store(v, reinterpret_cast<f32x4*>(ob + (size_t)row * SEQL));
    }
}

// ---- K0: prep (convert W; rope table) + 700 fill tiles ----
#define WQ (OUTW * HID / 4)          // 294912 float4 groups -> 1152 blocks
#define RQ (SEQL * 32)               // 65536 -> 256 blocks
#define PREP_BLOCKS 1408
#define FILL_PREP   700
#define FILL_P1     2180
__global__ void k_prep(const float* __restrict__ W,
                       unsigned short* __restrict__ Wbf, float2* __restrict__ rtab,
                       const int* __restrict__ mask, float* __restrict__ out) {
    if (blockIdx.x >= PREP_BLOCKS) {
        fill_tile(blockIdx.x - PREP_BLOCKS, threadIdx.x, mask, out);
        return;
    }
    int i = blockIdx.x * blockDim.x + threadIdx.x;
    if (i < WQ) {
        float4 v = reinterpret_cast<const float4*>(W)[i];
        ushort4 o;
        o.x = f2bf(v.x); o.y = f2bf(v.y); o.z = f2bf(v.z); o.w = f2bf(v.w);
        reinterpret_cast<ushort4*>(Wbf)[i] = o;
    } else if (i < WQ + RQ) {
        int idx = i - WQ;
        int n = idx >> 5, d = idx & 31;
        float theta = exp2f(-(float)d * (13.287712379549449f / 32.0f)); // 10000^(-d/32)
        float ang = (float)n * theta;
        rtab[idx] = make_float2(sinf(ang), cosf(ang));
    }
}

// ---- Phase 1: K1 proj GEMM (bids 0..767, X read f32 + in-reg convert)
//      + 2180 fill tiles (bids 768..2947) ----
__global__ __launch_bounds__(256, 4) void k_proj_fill(
    const float* __restrict__ X,              // [4096][768] f32
    const unsigned short* __restrict__ Wbf,   // [1536][768] bf16
    const float*  __restrict__ bias,          // [1536]
    const float2* __restrict__ rtab,          // [2048][32]
    unsigned short* __restrict__ Qbf,         // [2][12][2048][64] bf16
    unsigned short* __restrict__ Kbf,
    const int* __restrict__ mask,             // [2][2048]
    float* __restrict__ out)                  // [2][12][2048][2048]
{
    const int bid = blockIdx.x;
    const int tid = threadIdx.x;

    if (bid >= 768) {
        fill_tile(FILL_PREP + (bid - 768), tid, mask, out);
        return;
    }

    // ---- K1: projection GEMM + RoPE ----
    const int newbid = (bid & 7) * 96 + (bid >> 3); // bijective: 768 = 8*96
    const int slab = newbid / 12;                   // 0..63
    const int head = newbid % 12;                   // 0..11
    const int row0 = slab * 64;
    const int lane = tid & 63;
    const int w    = tid >> 6;
    const int wr = w & 1, wc = w >> 1;
    const int l31 = lane & 31, lhi = lane >> 5;
    const int x7  = l31 & 7;

    __shared__ __align__(16) unsigned short smem[12288];

    f32x16 acc[2];
    {
        float bj0 = bias[head * 128 + wc * 64 + l31];
        float bj1 = bias[head * 128 + wc * 64 + 32 + l31];
#pragma unroll
        for (int r = 0; r < 16; ++r) { acc[0][r] = bj0; acc[1][r] = bj1; }
    }

    const float* Abase = X + (size_t)row0 * HID;
    const unsigned short* Bbase = Wbf + (size_t)(head * 128) * HID;

    short8 ga[2], gb[4];
#pragma unroll
    for (int r = 0; r < 2; ++r) {
        int idx = tid + 256 * r, row = idx >> 3, s = idx & 7;
        ga[r] = cvt8(Abase + (size_t)row * HID + s * 8);
    }
#pragma unroll
    for (int r = 0; r < 4; ++r) {
        int idx = tid + 256 * r, row = idx >> 3, s = idx & 7;
        gb[r] = *reinterpret_cast<const short8*>(Bbase + (size_t)row * HID + s * 8);
    }
#pragma unroll
    for (int r = 0; r < 2; ++r) {
        int idx = tid + 256 * r, row = idx >> 3, s = idx & 7, ws = s ^ (row & 7);
        *reinterpret_cast<short8*>(smem + row * 64 + ws * 8) = ga[r];
    }
#pragma unroll
    for (int r = 0; r < 4; ++r) {
        int idx = tid + 256 * r, row = idx >> 3, s = idx & 7, ws = s ^ (row & 7);
        *reinterpret_cast<short8*>(smem + 4096 + row * 64 + ws * 8) = gb[r];
    }

    for (int t = 0; t < 12; ++t) {
        __syncthreads();
        if (t < 11) {
            const int kk = (t + 1) * 64;
#pragma unroll
            for (int r = 0; r < 2; ++r) {
                int idx = tid + 256 * r, row = idx >> 3, s = idx & 7;
                ga[r] = cvt8(Abase + (size_t)row * HID + kk + s * 8);
            }
#pragma unroll
            for (int r = 0; r < 4; ++r) {
                int idx = tid + 256 * r, row = idx >> 3, s = idx & 7;
                gb[r] = *reinterpret_cast<const short8*>(Bbase + (size_t)row * HID + kk + s * 8);
            }
        }
#pragma unroll
        for (int ks = 0; ks < 4; ++ks) {
            int sl = (ks * 2 + lhi) ^ x7;
            short8 a  = *reinterpret_cast<const short8*>(smem + (wr * 32 + l31) * 64 + sl * 8);
            short8 b0 = *reinterpret_cast<const short8*>(smem + 4096 + (wc * 64 + l31) * 64 + sl * 8);
            short8 b1 = *reinterpret_cast<const short8*>(smem + 4096 + (wc * 64 + 32 + l31) * 64 + sl * 8);
            acc[0] = __builtin_amdgcn_mfma_f32_32x32x16_bf16(a, b0, acc[0], 0, 0, 0);
            acc[1] = __builtin_amdgcn_mfma_f32_32x32x16_bf16(a, b1, acc[1], 0, 0, 0);
        }
        if (t < 11) {
            __syncthreads();
#pragma unroll
            for (int r = 0; r < 2; ++r) {
                int idx = tid + 256 * r, row = idx >> 3, s = idx & 7, ws = s ^ (row & 7);
                *reinterpret_cast<short8*>(smem + row * 64 + ws * 8) = ga[r];
            }
#pragma unroll
            for (int r = 0; r < 4; ++r) {
                int idx = tid + 256 * r, row = idx >> 3, s = idx & 7, ws = s ^ (row & 7);
                *reinterpret_cast<short8*>(smem + 4096 + row * 64 + ws * 8) = gb[r];
            }
        }
    }
    __syncthreads();

    // RoPE epilogue: two 32-row phases, hs[32][132] f32 in smem.
    float (*hs)[132] = reinterpret_cast<float (*)[132]>(smem);
    for (int s = 0; s < 2; ++s) {
        if (wr == s) {
#pragma unroll
            for (int j = 0; j < 2; ++j)
#pragma unroll
                for (int r = 0; r < 16; ++r) {
                    int rr = (r & 3) + 8 * (r >> 2) + 4 * lhi;  // 0..31
                    hs[rr][wc * 64 + j * 32 + l31] = acc[j][r];
                }
        }
        __syncthreads();
#pragma unroll 4
        for (int it = 0; it < 8; ++it) {
            int f   = tid + 256 * it;    // 0..2047
            int row = f >> 6;            // 0..31
            int u   = f & 63;
            int isK = u >> 5;
            int dp  = u & 31;
            int d0  = 2 * dp, d1 = d0 + 1;
            int cb  = isK * 64;
            int grow = row0 + s * 32 + row;
            int bI = grow >> 11;
            int n  = grow & 2047;
            float2 sc = rtab[n * 32 + dp];
            float v0 = hs[row][cb + d0];
            float v1 = hs[row][cb + d1];
            int p0 = (d0 < 32) ? (2 * d0 + 1) : (2 * d0 - 64);
            int p1 = (d1 < 32) ? (2 * d1 + 1) : (2 * d1 - 64);
            float pv0 = hs[row][cb + p0];
            float pv1 = hs[row][cb + p1];
            float sg0 = (d0 < 32) ? -1.0f : 1.0f;
            float sg1 = (d1 < 32) ? -1.0f : 1.0f;
            ushort2 st;
            st.x = f2bf(v0 * sc.y + sg0 * pv0 * sc.x);
            st.y = f2bf(v1 * sc.y + sg1 * pv1 * sc.x);
            unsigned short* dst = isK ? (unsigned short*)Kbf : (unsigned short*)Qbf;
            size_t idx = ((size_t)(bI * NH + head) * SEQL + n) * HD + d0;
            *reinterpret_cast<ushort2*>(dst + idx) = st;
        }
        __syncthreads();
    }
}

// ---- Phase 2: K2c compute tiles only; grid 3264 = 8*408 ----
__global__ __launch_bounds__(256) void k_logits(
    const unsigned short* __restrict__ Qbf,
    const unsigned short* __restrict__ Kbf,
    const int* __restrict__ mask,    // [2][2048]
    float* __restrict__ out)         // [2][12][2048][2048]
{
    const int bid = blockIdx.x;
    const int newbid = (bid & 7) * 408 + (bid >> 3);   // bijective: 3264 = 8*408
    const int tid = threadIdx.x;

    const int bh = newbid / 136;
    int j = newbid % 136;
    int ntv = 0;
    while (j >= 16 - ntv) { j -= 16 - ntv; ++ntv; }
    const int nt = ntv, mt = ntv + j;           // mt >= nt
    const int bI = bh / NH;
    float* outbase = out + (size_t)bh * SEQL * SEQL;

    const int lane = tid & 63;
    const int w = tid >> 6;
    const int rowHalf = w & 1, colHalf = w >> 1;
    const int l31 = lane & 31, lhi = lane >> 5;
    const int n0 = nt * 128 + rowHalf * 64;
    const int m0 = mt * 128 + colHalf * 64;

    f32x16 acc[2][2];
#pragma unroll
    for (int i = 0; i < 2; ++i)
#pragma unroll
        for (int jj = 0; jj < 2; ++jj)
#pragma unroll
            for (int r = 0; r < 16; ++r) acc[i][jj][r] = 0.0f;

    const unsigned short* Aq = Qbf + ((size_t)bh * SEQL + n0 + l31) * HD + 8 * lhi;
    const unsigned short* Bk = Kbf + ((size_t)bh * SEQL + m0 + l31) * HD + 8 * lhi;
#pragma unroll
    for (int t2 = 0; t2 < 4; ++t2) {
        short8 a0 = *reinterpret_cast<const short8*>(Aq + 16 * t2);
        short8 a1 = *reinterpret_cast<const short8*>(Aq + 32 * HD + 16 * t2);
        short8 b0 = *reinterpret_cast<const short8*>(Bk + 16 * t2);
        short8 b1 = *reinterpret_cast<const short8*>(Bk + 32 * HD + 16 * t2);
        acc[0][0] = __builtin_amdgcn_mfma_f32_32x32x16_bf16(a0, b0, acc[0][0], 0, 0, 0);
        acc[0][1] = __builtin_amdgcn_mfma_f32_32x32x16_bf16(a0, b1, acc[0][1], 0, 0, 0);
        acc[1][0] = __builtin_amdgcn_mfma_f32_32x32x16_bf16(a1, b0, acc[1][0], 0, 0, 0);
        acc[1][1] = __builtin_amdgcn_mfma_f32_32x32x16_bf16(a1, b1, acc[1][1], 0, 0, 0);
    }

    // LDS-transpose epilogue: two 32-row slabs (i = 0,1), f32x4 NT stores.
    // Mask/pads hoisted: gcol = mt*128 + (tid&31)*4 is loop-invariant.
    __shared__ float tl[64][128];   // 32 KB
    const int cg   = tid & 31;
    const int lr0  = tid >> 5;      // 0..7
    const int gcol = mt * 128 + cg * 4;
    const int4 mi  = *reinterpret_cast<const int4*>(mask + bI * SEQL + gcol);
    const float pads[4] = {(float)mi.x, (float)mi.y, (float)mi.z, (float)mi.w};
    float base[4];
#pragma unroll
    for (int e = 0; e < 4; ++e) base[e] = -(1.0f - pads[e]) * NEGBIG;

#pragma unroll
    for (int i = 0; i < 2; ++i) {
#pragma unroll
        for (int jj = 0; jj < 2; ++jj) {
#pragma unroll
            for (int r = 0; r < 16; ++r) {
                int rr = (r & 3) + 8 * (r >> 2) + 4 * lhi;    // 0..31
                tl[rowHalf * 32 + rr][colHalf * 64 + jj * 32 + l31] = acc[i][jj][r];
            }
        }
        __syncthreads();
#pragma unroll
        for (int it = 0; it < 8; ++it) {
            int lr   = lr0 + 8 * it;       // 0..63
            int grow = nt * 128 + (lr >> 5) * 64 + i * 32 + (lr & 31);
            f32x4 v = *reinterpret_cast<const f32x4*>(&tl[lr][cg * 4]);
#pragma unroll
            for (int e = 0; e < 4; ++e) {
                float vv = v[e] * pads[e] + base[e];
                if (gcol + e < grow) vv -= NEGBIG;
                v[e] = vv * 0.125f;
            }
            __builtin_nontemporal_store(v, reinterpret_cast<f32x4*>(outbase + (size_t)grow * SEQL + gcol));
        }
        __syncthreads();
    }
}

extern "C" void kernel_launch(void* const* d_in, const int* in_sizes, int n_in,
                              void* d_out, int out_size, void* d_ws, size_t ws_size,
                              hipStream_t stream) {
    const float* x    = (const float*)d_in[0];
    const int*   mask = (const int*)d_in[1];
    const float* W    = (const float*)d_in[2];
    const float* bias = (const float*)d_in[3];
    float* out = (float*)d_out;

    char* ws = (char*)d_ws;
    unsigned short* Wbf = (unsigned short*)(ws);                 // 2,359,296 B
    unsigned short* Qbf = (unsigned short*)(ws + 2359296);       // 6,291,456 B
    unsigned short* Kbf = (unsigned short*)(ws + 8650752);       // 6,291,456 B
    float2*         rtab = (float2*)(ws + 14942208);             //   524,288 B

    k_prep<<<dim3(PREP_BLOCKS + FILL_PREP), dim3(256), 0, stream>>>(W, Wbf, rtab, mask, out);
    k_proj_fill<<<dim3(768 + FILL_P1), dim3(256), 0, stream>>>(x, Wbf, bias, rtab, Qbf, Kbf, mask, out);
    k_logits<<<dim3(3264), dim3(256), 0, stream>>>(Qbf, Kbf, mask, out);
}

// Round 19
// 85.982 us; speedup vs baseline: 1.4268x; 1.0214x over previous
//
#include <hip/hip_runtime.h>
#include <hip/hip_bf16.h>
#include <cmath>

#define NH   12
#define HD   64
#define HID  768
#define NB   2
#define SEQL 2048
#define ROWS 4096   // NB*SEQL
#define OUTW 1536   // NH*HD*2

static constexpr float NEGBIG = 1000000000000.0f;

typedef __attribute__((ext_vector_type(4)))  float f32x4;
typedef __attribute__((ext_vector_type(8)))  short short8;
typedef __attribute__((ext_vector_type(16))) float f32x16;

__device__ __forceinline__ unsigned short f2bf(float f) {
    unsigned int u = __builtin_bit_cast(unsigned int, f);
    u += 0x7FFFu + ((u >> 16) & 1u);   // round-to-nearest-even
    return (unsigned short)(u >> 16);
}

__device__ __forceinline__ short8 cvt8(const float* __restrict__ p) {
    float4 v0 = *reinterpret_cast<const float4*>(p);
    float4 v1 = *reinterpret_cast<const float4*>(p + 4);
    short8 g;
    g[0] = (short)f2bf(v0.x); g[1] = (short)f2bf(v0.y);
    g[2] = (short)f2bf(v0.z); g[3] = (short)f2bf(v0.w);
    g[4] = (short)f2bf(v1.x); g[5] = (short)f2bf(v1.y);
    g[6] = (short)f2bf(v1.z); g[7] = (short)f2bf(v1.w);
    return g;
}

// Masked-tile fill: fid in [0,2880) enumerates (bh, nt, mt) with mt < nt.
__device__ __forceinline__ void fill_tile(int fid, int tid,
                                          const int* __restrict__ mask,
                                          float* __restrict__ out) {
    const int bh = fid / 120;
    int j = fid % 120;
    int ntv = 1;
    while (j >= ntv) { j -= ntv; ++ntv; }
    const int nt = ntv, mt = j;          // mt < nt
    const int bI = bh / NH;
    float* outbase = out + (size_t)bh * SEQL * SEQL;
    const int cg = tid & 31;
    const int r0 = tid >> 5;
    const int m0 = mt * 128 + cg * 4;
    const int4 mi = *reinterpret_cast<const int4*>(mask + bI * SEQL + m0);
    f32x4 v;
    v.x = ((float)mi.x - 2.0f) * (NEGBIG * 0.125f);
    v.y = ((float)mi.y - 2.0f) * (NEGBIG * 0.125f);
    v.z = ((float)mi.z - 2.0f) * (NEGBIG * 0.125f);
    v.w = ((float)mi.w - 2.0f) * (NEGBIG * 0.125f);
    float* ob = outbase + (size_t)(nt * 128) * SEQL + m0;
#pragma unroll
    for (int jj = 0; jj < 16; ++jj) {
        int row = r0 + 8 * jj;
        __builtin_nontemporal_store(v, reinterpret_cast<f32x4*>(ob + (size_t)row * SEQL));
    }
}

// ---- K0: prep (convert W; rope table) + 700 fill tiles ----
#define WQ (OUTW * HID / 4)          // 294912 float4 groups -> 1152 blocks
#define RQ (SEQL * 32)               // 65536 -> 256 blocks
#define PREP_BLOCKS 1408
#define FILL_PREP   700
#define FILL_P1     2180
__global__ void k_prep(const float* __restrict__ W,
                       unsigned short* __restrict__ Wbf, float2* __restrict__ rtab,
                       const int* __restrict__ mask, float* __restrict__ out) {
    if (blockIdx.x >= PREP_BLOCKS) {
        fill_tile(blockIdx.x - PREP_BLOCKS, threadIdx.x, mask, out);
        return;
    }
    int i = blockIdx.x * blockDim.x + threadIdx.x;
    if (i < WQ) {
        float4 v = reinterpret_cast<const float4*>(W)[i];
        ushort4 o;
        o.x = f2bf(v.x); o.y = f2bf(v.y); o.z = f2bf(v.z); o.w = f2bf(v.w);
        reinterpret_cast<ushort4*>(Wbf)[i] = o;
    } else if (i < WQ + RQ) {
        int idx = i - WQ;
        int n = idx >> 5, d = idx & 31;
        float theta = exp2f(-(float)d * (13.287712379549449f / 32.0f)); // 10000^(-d/32)
        float ang = (float)n * theta;
        rtab[idx] = make_float2(sinf(ang), cosf(ang));
    }
}

// ---- Phase 1: K1 proj GEMM (bids 0..767, X read f32 + in-reg convert)
//      + 2180 fill tiles (bids 768..2947) ----
__global__ __launch_bounds__(256, 4) void k_proj_fill(
    const float* __restrict__ X,              // [4096][768] f32
    const unsigned short* __restrict__ Wbf,   // [1536][768] bf16
    const float*  __restrict__ bias,          // [1536]
    const float2* __restrict__ rtab,          // [2048][32]
    unsigned short* __restrict__ Qbf,         // [2][12][2048][64] bf16
    unsigned short* __restrict__ Kbf,
    const int* __restrict__ mask,             // [2][2048]
    float* __restrict__ out)                  // [2][12][2048][2048]
{
    const int bid = blockIdx.x;
    const int tid = threadIdx.x;

    if (bid >= 768) {
        fill_tile(FILL_PREP + (bid - 768), tid, mask, out);
        return;
    }

    // ---- K1: projection GEMM + RoPE ----
    const int newbid = (bid & 7) * 96 + (bid >> 3); // bijective: 768 = 8*96
    const int slab = newbid / 12;                   // 0..63
    const int head = newbid % 12;                   // 0..11
    const int row0 = slab * 64;
    const int lane = tid & 63;
    const int w    = tid >> 6;
    const int wr = w & 1, wc = w >> 1;
    const int l31 = lane & 31, lhi = lane >> 5;
    const int x7  = l31 & 7;

    __shared__ __align__(16) unsigned short smem[12288];

    f32x16 acc[2];
    {
        float bj0 = bias[head * 128 + wc * 64 + l31];
        float bj1 = bias[head * 128 + wc * 64 + 32 + l31];
#pragma unroll
        for (int r = 0; r < 16; ++r) { acc[0][r] = bj0; acc[1][r] = bj1; }
    }

    const float* Abase = X + (size_t)row0 * HID;
    const unsigned short* Bbase = Wbf + (size_t)(head * 128) * HID;

    short8 ga[2], gb[4];
#pragma unroll
    for (int r = 0; r < 2; ++r) {
        int idx = tid + 256 * r, row = idx >> 3, s = idx & 7;
        ga[r] = cvt8(Abase + (size_t)row * HID + s * 8);
    }
#pragma unroll
    for (int r = 0; r < 4; ++r) {
        int idx = tid + 256 * r, row = idx >> 3, s = idx & 7;
        gb[r] = *reinterpret_cast<const short8*>(Bbase + (size_t)row * HID + s * 8);
    }
#pragma unroll
    for (int r = 0; r < 2; ++r) {
        int idx = tid + 256 * r, row = idx >> 3, s = idx & 7, ws = s ^ (row & 7);
        *reinterpret_cast<short8*>(smem + row * 64 + ws * 8) = ga[r];
    }
#pragma unroll
    for (int r = 0; r < 4; ++r) {
        int idx = tid + 256 * r, row = idx >> 3, s = idx & 7, ws = s ^ (row & 7);
        *reinterpret_cast<short8*>(smem + 4096 + row * 64 + ws * 8) = gb[r];
    }

    for (int t = 0; t < 12; ++t) {
        __syncthreads();
        if (t < 11) {
            const int kk = (t + 1) * 64;
#pragma unroll
            for (int r = 0; r < 2; ++r) {
                int idx = tid + 256 * r, row = idx >> 3, s = idx & 7;
                ga[r] = cvt8(Abase + (size_t)row * HID + kk + s * 8);
            }
#pragma unroll
            for (int r = 0; r < 4; ++r) {
                int idx = tid + 256 * r, row = idx >> 3, s = idx & 7;
                gb[r] = *reinterpret_cast<const short8*>(Bbase + (size_t)row * HID + kk + s * 8);
            }
        }
#pragma unroll
        for (int ks = 0; ks < 4; ++ks) {
            int sl = (ks * 2 + lhi) ^ x7;
            short8 a  = *reinterpret_cast<const short8*>(smem + (wr * 32 + l31) * 64 + sl * 8);
            short8 b0 = *reinterpret_cast<const short8*>(smem + 4096 + (wc * 64 + l31) * 64 + sl * 8);
            short8 b1 = *reinterpret_cast<const short8*>(smem + 4096 + (wc * 64 + 32 + l31) * 64 + sl * 8);
            acc[0] = __builtin_amdgcn_mfma_f32_32x32x16_bf16(a, b0, acc[0], 0, 0, 0);
            acc[1] = __builtin_amdgcn_mfma_f32_32x32x16_bf16(a, b1, acc[1], 0, 0, 0);
        }
        if (t < 11) {
            __syncthreads();
#pragma unroll
            for (int r = 0; r < 2; ++r) {
                int idx = tid + 256 * r, row = idx >> 3, s = idx & 7, ws = s ^ (row & 7);
                *reinterpret_cast<short8*>(smem + row * 64 + ws * 8) = ga[r];
            }
#pragma unroll
            for (int r = 0; r < 4; ++r) {
                int idx = tid + 256 * r, row = idx >> 3, s = idx & 7, ws = s ^ (row & 7);
                *reinterpret_cast<short8*>(smem + 4096 + row * 64 + ws * 8) = gb[r];
            }
        }
    }
    __syncthreads();

    // RoPE epilogue: two 32-row phases, hs[32][132] f32 in smem.
    float (*hs)[132] = reinterpret_cast<float (*)[132]>(smem);
    for (int s = 0; s < 2; ++s) {
        if (wr == s) {
#pragma unroll
            for (int j = 0; j < 2; ++j)
#pragma unroll
                for (int r = 0; r < 16; ++r) {
                    int rr = (r & 3) + 8 * (r >> 2) + 4 * lhi;  // 0..31
                    hs[rr][wc * 64 + j * 32 + l31] = acc[j][r];
                }
        }
        __syncthreads();
#pragma unroll 4
        for (int it = 0; it < 8; ++it) {
            int f   = tid + 256 * it;    // 0..2047
            int row = f >> 6;            // 0..31
            int u   = f & 63;
            int isK = u >> 5;
            int dp  = u & 31;
            int d0  = 2 * dp, d1 = d0 + 1;
            int cb  = isK * 64;
            int grow = row0 + s * 32 + row;
            int bI = grow >> 11;
            int n  = grow & 2047;
            float2 sc = rtab[n * 32 + dp];
            float v0 = hs[row][cb + d0];
            float v1 = hs[row][cb + d1];
            int p0 = (d0 < 32) ? (2 * d0 + 1) : (2 * d0 - 64);
            int p1 = (d1 < 32) ? (2 * d1 + 1) : (2 * d1 - 64);
            float pv0 = hs[row][cb + p0];
            float pv1 = hs[row][cb + p1];
            float sg0 = (d0 < 32) ? -1.0f : 1.0f;
            float sg1 = (d1 < 32) ? -1.0f : 1.0f;
            ushort2 st;
            st.x = f2bf(v0 * sc.y + sg0 * pv0 * sc.x);
            st.y = f2bf(v1 * sc.y + sg1 * pv1 * sc.x);
            unsigned short* dst = isK ? (unsigned short*)Kbf : (unsigned short*)Qbf;
            size_t idx = ((size_t)(bI * NH + head) * SEQL + n) * HD + d0;
            *reinterpret_cast<ushort2*>(dst + idx) = st;
        }
        __syncthreads();
    }
}

// ---- Phase 2: K2c compute tiles only; grid 3264 = 8*408 ----
// LDS-staged Q/K tiles: coalesced contiguous 16 KB loads per tile, XOR-swizzled
// LDS; replaces 32-way-scattered direct fragment loads. LDS reused as tl.
__global__ __launch_bounds__(256) void k_logits(
    const unsigned short* __restrict__ Qbf,
    const unsigned short* __restrict__ Kbf,
    const int* __restrict__ mask,    // [2][2048]
    float* __restrict__ out)         // [2][12][2048][2048]
{
    const int bid = blockIdx.x;
    const int newbid = (bid & 7) * 408 + (bid >> 3);   // bijective: 3264 = 8*408
    const int tid = threadIdx.x;

    const int bh = newbid / 136;
    int j = newbid % 136;
    int ntv = 0;
    while (j >= 16 - ntv) { j -= 16 - ntv; ++ntv; }
    const int nt = ntv, mt = ntv + j;           // mt >= nt
    const int bI = bh / NH;
    float* outbase = out + (size_t)bh * SEQL * SEQL;

    const int lane = tid & 63;
    const int w = tid >> 6;
    const int rowHalf = w & 1, colHalf = w >> 1;
    const int l31 = lane & 31, lhi = lane >> 5;
    const int x7 = l31 & 7;

    // 32 KB: Q tile [0,8192) shorts, K tile [8192,16384); reused as tl after.
    __shared__ __align__(16) unsigned short smem[16384];

    // stage Q tile (rows nt*128..+127, all 64 cols) -- contiguous 16 KB
    const unsigned short* Qsrc = Qbf + ((size_t)bh * SEQL + nt * 128) * HD;
    const unsigned short* Ksrc = Kbf + ((size_t)bh * SEQL + mt * 128) * HD;
    {
        short8 st[4];
#pragma unroll
        for (int r = 0; r < 4; ++r) {
            int idx = tid + 256 * r;               // 0..1023
            st[r] = *reinterpret_cast<const short8*>(Qsrc + idx * 8);
        }
#pragma unroll
        for (int r = 0; r < 4; ++r) {
            int idx = tid + 256 * r, row = idx >> 3, s = idx & 7, ws = s ^ (row & 7);
            *reinterpret_cast<short8*>(smem + row * 64 + ws * 8) = st[r];
        }
#pragma unroll
        for (int r = 0; r < 4; ++r) {
            int idx = tid + 256 * r;
            st[r] = *reinterpret_cast<const short8*>(Ksrc + idx * 8);
        }
#pragma unroll
        for (int r = 0; r < 4; ++r) {
            int idx = tid + 256 * r, row = idx >> 3, s = idx & 7, ws = s ^ (row & 7);
            *reinterpret_cast<short8*>(smem + 8192 + row * 64 + ws * 8) = st[r];
        }
    }
    __syncthreads();

    f32x16 acc[2][2];
#pragma unroll
    for (int i = 0; i < 2; ++i)
#pragma unroll
        for (int jj = 0; jj < 2; ++jj)
#pragma unroll
            for (int r = 0; r < 16; ++r) acc[i][jj][r] = 0.0f;

#pragma unroll
    for (int ks = 0; ks < 4; ++ks) {
        int sl = (ks * 2 + lhi) ^ x7;
        short8 a0 = *reinterpret_cast<const short8*>(smem + (rowHalf * 64 + l31) * 64      + sl * 8);
        short8 a1 = *reinterpret_cast<const short8*>(smem + (rowHalf * 64 + 32 + l31) * 64 + sl * 8);
        short8 b0 = *reinterpret_cast<const short8*>(smem + 8192 + (colHalf * 64 + l31) * 64      + sl * 8);
        short8 b1 = *reinterpret_cast<const short8*>(smem + 8192 + (colHalf * 64 + 32 + l31) * 64 + sl * 8);
        acc[0][0] = __builtin_amdgcn_mfma_f32_32x32x16_bf16(a0, b0, acc[0][0], 0, 0, 0);
        acc[0][1] = __builtin_amdgcn_mfma_f32_32x32x16_bf16(a0, b1, acc[0][1], 0, 0, 0);
        acc[1][0] = __builtin_amdgcn_mfma_f32_32x32x16_bf16(a1, b0, acc[1][0], 0, 0, 0);
        acc[1][1] = __builtin_amdgcn_mfma_f32_32x32x16_bf16(a1, b1, acc[1][1], 0, 0, 0);
    }
    __syncthreads();   // all LDS reads done before reuse as tl

    // LDS-transpose epilogue: two 32-row slabs (i = 0,1), f32x4 NT stores.
    // Mask/pads hoisted: gcol = mt*128 + (tid&31)*4 is loop-invariant.
    float (*tl)[128] = reinterpret_cast<float (*)[128]>(smem);   // 32 KB
    const int cg   = tid & 31;
    const int lr0  = tid >> 5;      // 0..7
    const int gcol = mt * 128 + cg * 4;
    const int4 mi  = *reinterpret_cast<const int4*>(mask + bI * SEQL + gcol);
    const float pads[4] = {(float)mi.x, (float)mi.y, (float)mi.z, (float)mi.w};
    float base[4];
#pragma unroll
    for (int e = 0; e < 4; ++e) base[e] = -(1.0f - pads[e]) * NEGBIG;

#pragma unroll
    for (int i = 0; i < 2; ++i) {
#pragma unroll
        for (int jj = 0; jj < 2; ++jj) {
#pragma unroll
            for (int r = 0; r < 16; ++r) {
                int rr = (r & 3) + 8 * (r >> 2) + 4 * lhi;    // 0..31
                tl[rowHalf * 32 + rr][colHalf * 64 + jj * 32 + l31] = acc[i][jj][r];
            }
        }
        __syncthreads();
#pragma unroll
        for (int it = 0; it < 8; ++it) {
            int lr   = lr0 + 8 * it;       // 0..63
            int grow = nt * 128 + (lr >> 5) * 64 + i * 32 + (lr & 31);
            f32x4 v = *reinterpret_cast<const f32x4*>(&tl[lr][cg * 4]);
#pragma unroll
            for (int e = 0; e < 4; ++e) {
                float vv = v[e] * pads[e] + base[e];
                if (gcol + e < grow) vv -= NEGBIG;
                v[e] = vv * 0.125f;
            }
            __builtin_nontemporal_store(v, reinterpret_cast<f32x4*>(outbase + (size_t)grow * SEQL + gcol));
        }
        __syncthreads();
    }
}

extern "C" void kernel_launch(void* const* d_in, const int* in_sizes, int n_in,
                              void* d_out, int out_size, void* d_ws, size_t ws_size,
                              hipStream_t stream) {
    const float* x    = (const float*)d_in[0];
    const int*   mask = (const int*)d_in[1];
    const float* W    = (const float*)d_in[2];
    const float* bias = (const float*)d_in[3];
    float* out = (float*)d_out;

    char* ws = (char*)d_ws;
    unsigned short* Wbf = (unsigned short*)(ws);                 // 2,359,296 B
    unsigned short* Qbf = (unsigned short*)(ws + 2359296);       // 6,291,456 B
    unsigned short* Kbf = (unsigned short*)(ws + 8650752);       // 6,291,456 B
    float2*         rtab = (float2*)(ws + 14942208);             //   524,288 B

    k_prep<<<dim3(PREP_BLOCKS + FILL_PREP), dim3(256), 0, stream>>>(W, Wbf, rtab, mask, out);
    k_proj_fill<<<dim3(768 + FILL_P1), dim3(256), 0, stream>>>(x, Wbf, bias, rtab, Qbf, Kbf, mask, out);
    k_logits<<<dim3(3264), dim3(256), 0, stream>>>(Qbf, Kbf, mask, out);
}